// Round 2
// baseline (181.377 us; speedup 1.0000x reference)
//
#include <hip/hip_runtime.h>

// SWD18: per-feature cyclic window-of-5 sort (reduction verified absmax=0, R1-R7):
// for column i, sort rows {5m + (i%5) + j mod L, j=0..4} ascending, in place.
// q, k are dead inputs.
//
// R8: 30 upfront scalar loads (rows [R0-5,R0+25)), verified A/B window mux +
// 9-comparator sorts, NT stores. 96 MB read + 64 MB write -> ~25 us kernel.
// R9: XCD-chunk swizzle (T1) -> dur_us flat (179.9 vs 177.7, metric is
// ~155 us harness fills + kernel; cross-round noise +-2 us hides <3 us).
//
// R10: structural read-amp cut, no cache bets. Amp = (SROWS+10)/SROWS.
// SROWS 20 -> 50: amp 1.5x -> 1.2x, read 96 -> 76.8 MB. R6 showed a big flat
// register array gets sunk by the compiler (re-loads); so stage through a
// 5-slot x 5-row rolling ring (25 live floats, prefetch distance 2 groups),
// fully unrolled so every ring index is compile-time (stays in VGPRs).
// Grid: 80 strips x 2 halves x 8 batches = 1280 blocks = exactly 5/CU
// (no tail). Swizzle kept: nwg=1280 -> each XCD owns one batch; halo
// neighbors co-resident on its L2. Predicted kernel ~21 us (traffic
// 141 MB @ 6.6 TB/s); bench dur_us ~175-177.

constexpr int L  = 4000;
constexpr int D  = 512;
constexpr int SROWS   = 50;            // output rows per thread
constexpr int NG      = SROWS / 5;     // 10 groups per strip
constexpr int NSTRIPS = L / SROWS;     // 80

// optimal 9-comparator sorting network for 5, ascending
#define CE(a, b) { float lo_ = fminf(a, b); float hi_ = fmaxf(a, b); (a) = lo_; (b) = hi_; }

__global__ __launch_bounds__(256, 6)
void swd18_ring(const float* __restrict__ v, float* __restrict__ out) {
    // ---- bijective XCD-chunk swizzle (m204 formula) ----
    // nwg=1280 -> q=160, rm=0: XCD x owns batch x entirely; adjacent strips
    // (halo sharers) are co-resident on the same per-XCD L2.
    const int nwg = gridDim.x * gridDim.y;
    const int lid = blockIdx.x + gridDim.x * blockIdx.y;   // dispatch order
    const int q   = nwg >> 3;
    const int rm  = nwg & 7;
    const int xcd = lid & 7;
    const int pos = lid >> 3;
    const int nid = (xcd < rm ? xcd * (q + 1) : rm * (q + 1) + (xcd - rm) * q) + pos;

    const int b     = nid / (NSTRIPS * 2);
    const int rr    = nid % (NSTRIPS * 2);
    const int half  = rr & 1;
    const int strip = rr >> 1;                     // 0..NSTRIPS-1
    const int i     = half * 256 + threadIdx.x;    // column 0..511

    const float* __restrict__ vb = v   + (size_t)b * (L * D);
    float*       __restrict__ ob = out + (size_t)b * (L * D);

    const int R0 = strip * SROWS;                  // multiple of 5

    // ---- 5-slot rolling ring: slot(g) = (g+1) % 5 holds group g (5 rows).
    // Group g covers rows R0+5g .. R0+5g+4 (cyclic wrap only at g=-1 / g=NG).
    float s[5][5];

    auto loadg = [&](int slot, int g) {
        int row = R0 + 5 * g;
        if (row < 0)  row += L;                    // strip 0, g=-1
        if (row >= L) row -= L;                    // last strip, g=NG
#pragma unroll
        for (int j = 0; j < 5; ++j)
            s[slot][j] = vb[(size_t)(row + j) * D + i];
    };

    // preload groups -1,0,1,2 -> slots 0,1,2,3 (prefetch distance 2)
    loadg(0, -1);
    loadg(1,  0);
    loadg(2,  1);
    loadg(3,  2);

    const int rc = i % 5;
    const bool e0 = rc == 0, e1 = rc == 1, e2 = rc == 2, e3 = rc == 3;

#pragma unroll
    for (int k = 0; k < NG; ++k) {                 // k fully unrolled: all
        if (k + 3 <= NG)                           // ring indices compile-time
            loadg((k + 4) % 5, k + 3);             // overwrites dead group k-1... (slot check verified)

        const float* P = s[k % 5];                 // group k-1
        const float* C = s[(k + 1) % 5];           // group k
        const float* N = s[(k + 2) % 5];           // group k+1

        // verified R7 A/B window (p[0..4]=P, p[5..9]=C, p[10..14]=N)
        float A0 = e0 ? P[0] : e1 ? P[1] : e2 ? P[2] : e3 ? P[3] : P[4];
        float A1 = e0 ? P[1] : e1 ? P[2] : e2 ? P[3] : e3 ? P[4] : C[0];
        float A2 = e0 ? P[2] : e1 ? P[3] : e2 ? P[4] : e3 ? C[0] : C[1];
        float A3 = e0 ? P[3] : e1 ? P[4] : e2 ? C[0] : e3 ? C[1] : C[2];
        float A4 = e0 ? P[4] : e1 ? C[0] : e2 ? C[1] : e3 ? C[2] : C[3];
        float B0 = e0 ? C[0] : e1 ? C[1] : e2 ? C[2] : e3 ? C[3] : C[4];
        float B1 = e0 ? C[1] : e1 ? C[2] : e2 ? C[3] : e3 ? C[4] : N[0];
        float B2 = e0 ? C[2] : e1 ? C[3] : e2 ? C[4] : e3 ? N[0] : N[1];
        float B3 = e0 ? C[3] : e1 ? C[4] : e2 ? N[0] : e3 ? N[1] : N[2];
        float B4 = e0 ? C[4] : e1 ? N[0] : e2 ? N[1] : e3 ? N[2] : N[3];

        CE(A0, A1) CE(A3, A4) CE(A2, A4) CE(A2, A3) CE(A1, A4)
        CE(A0, A3) CE(A0, A2) CE(A1, A3) CE(A1, A2)
        CE(B0, B1) CE(B3, B4) CE(B2, B4) CE(B2, B3) CE(B1, B4)
        CE(B0, B3) CE(B0, B2) CE(B1, B3) CE(B1, B2)

        // out[R0+5k+t] = (t < rc) ? A[t+5-rc] : B[t-rc]
        float f0 = e0 ? B0 : e1 ? A4 : e2 ? A3 : e3 ? A2 : A1;
        float f1 = e0 ? B1 : e1 ? B0 : e2 ? A4 : e3 ? A3 : A2;
        float f2 = e0 ? B2 : e1 ? B1 : e2 ? B0 : e3 ? A4 : A3;
        float f3 = e0 ? B3 : e1 ? B2 : e2 ? B1 : e3 ? B0 : A4;
        float f4 = e0 ? B4 : e1 ? B3 : e2 ? B2 : e3 ? B1 : B0;

        float* o = ob + (size_t)(R0 + 5 * k) * D + i;   // output rows never wrap
        __builtin_nontemporal_store(f0, o + 0 * D);
        __builtin_nontemporal_store(f1, o + 1 * D);
        __builtin_nontemporal_store(f2, o + 2 * D);
        __builtin_nontemporal_store(f3, o + 3 * D);
        __builtin_nontemporal_store(f4, o + 4 * D);
    }
}

#undef CE

extern "C" void kernel_launch(void* const* d_in, const int* in_sizes, int n_in,
                              void* d_out, int out_size, void* d_ws, size_t ws_size,
                              hipStream_t stream) {
    // setup_inputs order: q, k, v — only v is used by the reference forward.
    const float* v = (const float*)d_in[2];
    float* out = (float*)d_out;

    const int B = in_sizes[2] / (L * D);           // 8 for the bench shape
    dim3 grid(NSTRIPS * 2, B);                     // 160 x 8 = 1280 blocks of 256
    swd18_ring<<<grid, dim3(256), 0, stream>>>(v, out);
}